// Round 5
// baseline (235.686 us; speedup 1.0000x reference)
//
#include <hip/hip_runtime.h>

#define H 4
#define D1 128
#define D2 256
#define CIN 16
#define SLOPE 0.2f
#define LOG2E 1.4426950408889634f

__device__ __forceinline__ float bflo(unsigned u) { return __uint_as_float(u << 16); }
__device__ __forceinline__ float bfhi(unsigned u) { return __uint_as_float(u & 0xFFFF0000u); }
__device__ __forceinline__ unsigned short f2bf(float f) {
    unsigned int u = __float_as_uint(f);
    u += 0x7FFFu + ((u >> 16) & 1u);
    return (unsigned short)(u >> 16);
}

// ============ CSR build ============
__global__ void k_hist(const int* __restrict__ ei, int E, int ET,
                       int* __restrict__ deg) {
    int idx = blockIdx.x * blockDim.x + threadIdx.x;
    if (idx >= ET) return;
    int dst = (idx < E) ? ei[E + idx] : idx - E;
    atomicAdd(&deg[dst], 1);
}

// single-block exclusive scan over deg[0..n) -> rp; also zeroes cur.
// 1024 threads x 32 elems = up to 32768 (n = 30000 here).
__global__ __launch_bounds__(1024) void k_scan_one(
        const int* __restrict__ deg, int* __restrict__ rp,
        int* __restrict__ cur, int n) {
    __shared__ int wsum[16];
    int t = threadIdx.x;
    int lane = t & 63, w = t >> 6;
    int base = t * 32;
    int loc[32];
    int s = 0;
#pragma unroll
    for (int k = 0; k < 32; ++k) {
        int idx = base + k;
        int v = (idx < n) ? deg[idx] : 0;
        loc[k] = s;
        s += v;
    }
    // wave-inclusive scan of per-thread totals
    int inc = s;
#pragma unroll
    for (int off = 1; off < 64; off <<= 1) {
        int u = __shfl_up(inc, off, 64);
        if (lane >= off) inc += u;
    }
    int excl = inc - s;
    if (lane == 63) wsum[w] = inc;
    __syncthreads();
    if (w == 0) {
        int v = (lane < 16) ? wsum[lane] : 0;
        int winc = v;
#pragma unroll
        for (int off = 1; off < 16; off <<= 1) {
            int u = __shfl_up(winc, off, 64);
            if (lane >= off) winc += u;
        }
        if (lane < 16) wsum[lane] = winc - v;
    }
    __syncthreads();
    int offw = wsum[w] + excl;
#pragma unroll
    for (int k = 0; k < 32; ++k) {
        int idx = base + k;
        if (idx < n) { rp[idx] = offw + loc[k]; cur[idx] = 0; }
    }
}

__global__ void k_fill(const int* __restrict__ ei, int E, int ET,
                       const int* __restrict__ rp, int* __restrict__ cur,
                       int* __restrict__ eord) {
    int idx = blockIdx.x * blockDim.x + threadIdx.x;
    if (idx >= ET) return;
    int src, dst;
    if (idx < E) { src = ei[idx]; dst = ei[E + idx]; }
    else         { src = dst = idx - E; }
    int pos = atomicAdd(&cur[dst], 1);
    eord[rp[dst] + pos] = src;
}

// ============ layer-1 linear ============
__global__ __launch_bounds__(256) void k_lin1(
        const float* __restrict__ x, const float* __restrict__ lb,
        const float* __restrict__ ub,
        const float* __restrict__ Wl, const float* __restrict__ bl,
        const float* __restrict__ Wr, const float* __restrict__ br,
        unsigned short* __restrict__ xl, float* __restrict__ xr, int n) {
    __shared__ float Wls[CIN][D1];
    __shared__ float Wrs[CIN][D1];
    __shared__ float ys[16][CIN];
    int t = threadIdx.x;
    int i0 = blockIdx.x * 16;
#pragma unroll
    for (int i = 0; i < 8; ++i) {
        int flat = t + 256 * i;
        int k = flat >> 7, c = flat & 127;
        Wls[k][c] = Wl[k * D1 + c];
        Wrs[k][c] = Wr[k * D1 + c];
    }
    {
        int node = t >> 4, k = t & 15;
        int gi = i0 + node;
        float xv = (gi < n) ? x[(size_t)gi * CIN + k] : 0.f;
        ys[node][k] = (xv - lb[k]) / (ub[k] - lb[k]);
    }
    __syncthreads();
    int c = t & 127;
    bool left = t < 128;
    const float (*Ws)[D1] = left ? Wls : Wrs;
    float bias = left ? bl[c] : br[c];
    for (int j = 0; j < 16; ++j) {
        float acc = bias;
#pragma unroll
        for (int k = 0; k < CIN; ++k) acc += ys[j][k] * Ws[k][c];
        int gi = i0 + j;
        if (gi < n) {
            if (left) xl[(size_t)gi * D1 + c] = f2bf(acc);
            else      xr[(size_t)gi * D1 + c] = acc;
        }
    }
}

// ============ layer-2 linear (tiled fp32 GEMM) ============
__global__ __launch_bounds__(256) void k_lin2(
        const float* __restrict__ h1,
        const float* __restrict__ Wl, const float* __restrict__ bl,
        const float* __restrict__ Wr, const float* __restrict__ br,
        unsigned short* __restrict__ xl, float* __restrict__ xr, int n) {
    __shared__ float As[32][132];
    __shared__ float Bs[32][128];
    int t = threadIdx.x;
    int tx = t & 15, ty = t >> 4;
    int row0 = blockIdx.x * 128;
    int NT = blockIdx.y;
    const float* W = (NT < 2) ? Wl : Wr;
    const float* bias = (NT < 2) ? bl : br;
    int nc0 = (NT & 1) * 128;
    float acc[8][8];
#pragma unroll
    for (int u = 0; u < 8; ++u)
#pragma unroll
        for (int v = 0; v < 8; ++v) acc[u][v] = 0.f;

    for (int kc = 0; kc < 4; ++kc) {
#pragma unroll
        for (int i = 0; i < 4; ++i) {
            int flat = t + 256 * i;
            int row = flat >> 3, q = flat & 7;
            float4 vA = make_float4(0.f, 0.f, 0.f, 0.f);
            if (row0 + row < n)
                vA = *(const float4*)(h1 + (size_t)(row0 + row) * D1 + kc * 32 + q * 4);
            As[q * 4 + 0][row] = vA.x;
            As[q * 4 + 1][row] = vA.y;
            As[q * 4 + 2][row] = vA.z;
            As[q * 4 + 3][row] = vA.w;
        }
#pragma unroll
        for (int i = 0; i < 4; ++i) {
            int flat = t + 256 * i;
            int k = flat >> 5, q = flat & 31;
            float4 vB = *(const float4*)(W + (size_t)(kc * 32 + k) * D2 + nc0 + q * 4);
            *(float4*)&Bs[k][q * 4] = vB;
        }
        __syncthreads();
#pragma unroll
        for (int k = 0; k < 32; ++k) {
            float4 A0 = *(const float4*)&As[k][ty * 8];
            float4 A1 = *(const float4*)&As[k][ty * 8 + 4];
            float4 B0 = *(const float4*)&Bs[k][tx * 4];
            float4 B1 = *(const float4*)&Bs[k][tx * 4 + 64];
            float a_[8] = {A0.x, A0.y, A0.z, A0.w, A1.x, A1.y, A1.z, A1.w};
            float b_[8] = {B0.x, B0.y, B0.z, B0.w, B1.x, B1.y, B1.z, B1.w};
#pragma unroll
            for (int u = 0; u < 8; ++u)
#pragma unroll
                for (int v = 0; v < 8; ++v) acc[u][v] += a_[u] * b_[v];
        }
        __syncthreads();
    }

#pragma unroll
    for (int u = 0; u < 8; ++u) {
        int row = row0 + ty * 8 + u;
        if (row >= n) continue;
        int cb = nc0 + tx * 4;
        int cb2 = cb + 64;
        float o0 = acc[u][0] + bias[cb + 0];
        float o1 = acc[u][1] + bias[cb + 1];
        float o2 = acc[u][2] + bias[cb + 2];
        float o3 = acc[u][3] + bias[cb + 3];
        float p0 = acc[u][4] + bias[cb2 + 0];
        float p1 = acc[u][5] + bias[cb2 + 1];
        float p2 = acc[u][6] + bias[cb2 + 2];
        float p3 = acc[u][7] + bias[cb2 + 3];
        if (NT < 2) {
            ushort4 s0; s0.x = f2bf(o0); s0.y = f2bf(o1); s0.z = f2bf(o2); s0.w = f2bf(o3);
            ushort4 s1; s1.x = f2bf(p0); s1.y = f2bf(p1); s1.z = f2bf(p2); s1.w = f2bf(p3);
            *(ushort4*)(xl + (size_t)row * D2 + cb)  = s0;
            *(ushort4*)(xl + (size_t)row * D2 + cb2) = s1;
        } else {
            *(float4*)(xr + (size_t)row * D2 + cb)  = make_float4(o0, o1, o2, o3);
            *(float4*)(xr + (size_t)row * D2 + cb2) = make_float4(p0, p1, p2, p3);
        }
    }
}

// ============ fused GATv2 aggregation, layer 1 ============
// 256 thr = 4 nodes (64 lanes = 1 wave each); 2 comps/lane; head = 16 lanes.
// Scalarized node state, main/tail split, prefetched gathers.
__global__ __launch_bounds__(256) void k_agg1(
        const unsigned short* __restrict__ xl, const float* __restrict__ xr,
        const float* __restrict__ att, const float* __restrict__ bias,
        const int* __restrict__ rp, const int* __restrict__ deg,
        const int* __restrict__ eord, float* __restrict__ h1, int n) {
    int t = threadIdx.x;
    int node = blockIdx.x * 4 + (t >> 6);
    int l = t & 63;
    int nd = (node < n) ? node : n - 1;
    float2 xrv = *(const float2*)(xr + (size_t)nd * D1 + 2 * l);
    float2 av  = *(const float2*)(att + 2 * l);
    av.x *= LOG2E; av.y *= LOG2E;
    int start = __builtin_amdgcn_readfirstlane(rp[nd]);
    int cnt   = (node < n) ? deg[nd] : 0;
    cnt = __builtin_amdgcn_readfirstlane(cnt);
    const unsigned* xlp = (const unsigned*)xl;   // row stride 64 uints
    float d = 0.f, a0 = 0.f, a1 = 0.f;
    int cnt4 = cnt & ~3;
    unsigned r0, r1, r2, r3;
    if (cnt4 > 0) {
        int i0 = eord[start + 0], i1 = eord[start + 1];
        int i2 = eord[start + 2], i3 = eord[start + 3];
        r0 = xlp[(size_t)i0 * 64 + l]; r1 = xlp[(size_t)i1 * 64 + l];
        r2 = xlp[(size_t)i2 * 64 + l]; r3 = xlp[(size_t)i3 * 64 + l];
    }
    for (int j = 0; j < cnt4; j += 4) {
        unsigned p0 = r0, p1 = r1, p2 = r2, p3 = r3;
        int jn = j + 4;
        if (jn < cnt4) {
            int i0 = eord[start + jn + 0], i1 = eord[start + jn + 1];
            int i2 = eord[start + jn + 2], i3 = eord[start + jn + 3];
            r0 = xlp[(size_t)i0 * 64 + l]; r1 = xlp[(size_t)i1 * 64 + l];
            r2 = xlp[(size_t)i2 * 64 + l]; r3 = xlp[(size_t)i3 * 64 + l];
        }
        float x00 = bflo(p0), x01 = bfhi(p0);
        float x10 = bflo(p1), x11 = bfhi(p1);
        float x20 = bflo(p2), x21 = bfhi(p2);
        float x30 = bflo(p3), x31 = bfhi(p3);
        float v, lg0, lg1, lg2, lg3;
        v = x00 + xrv.x; v = fmaxf(v, SLOPE * v); lg0  = av.x * v;
        v = x01 + xrv.y; v = fmaxf(v, SLOPE * v); lg0 += av.y * v;
        v = x10 + xrv.x; v = fmaxf(v, SLOPE * v); lg1  = av.x * v;
        v = x11 + xrv.y; v = fmaxf(v, SLOPE * v); lg1 += av.y * v;
        v = x20 + xrv.x; v = fmaxf(v, SLOPE * v); lg2  = av.x * v;
        v = x21 + xrv.y; v = fmaxf(v, SLOPE * v); lg2 += av.y * v;
        v = x30 + xrv.x; v = fmaxf(v, SLOPE * v); lg3  = av.x * v;
        v = x31 + xrv.y; v = fmaxf(v, SLOPE * v); lg3 += av.y * v;
        lg0 += __shfl_xor(lg0, 8); lg1 += __shfl_xor(lg1, 8);
        lg2 += __shfl_xor(lg2, 8); lg3 += __shfl_xor(lg3, 8);
        lg0 += __shfl_xor(lg0, 4); lg1 += __shfl_xor(lg1, 4);
        lg2 += __shfl_xor(lg2, 4); lg3 += __shfl_xor(lg3, 4);
        lg0 += __shfl_xor(lg0, 2); lg1 += __shfl_xor(lg1, 2);
        lg2 += __shfl_xor(lg2, 2); lg3 += __shfl_xor(lg3, 2);
        lg0 += __shfl_xor(lg0, 1); lg1 += __shfl_xor(lg1, 1);
        lg2 += __shfl_xor(lg2, 1); lg3 += __shfl_xor(lg3, 1);
        float e0 = exp2f(lg0), e1 = exp2f(lg1);
        float e2 = exp2f(lg2), e3 = exp2f(lg3);
        d += (e0 + e1) + (e2 + e3);
        a0 += e0 * x00 + e1 * x10 + e2 * x20 + e3 * x30;
        a1 += e0 * x01 + e1 * x11 + e2 * x21 + e3 * x31;
    }
    for (int j = cnt4; j < cnt; ++j) {
        int s0 = eord[start + j];
        unsigned p0 = xlp[(size_t)s0 * 64 + l];
        float x00 = bflo(p0), x01 = bfhi(p0);
        float v, lg0;
        v = x00 + xrv.x; v = fmaxf(v, SLOPE * v); lg0  = av.x * v;
        v = x01 + xrv.y; v = fmaxf(v, SLOPE * v); lg0 += av.y * v;
        lg0 += __shfl_xor(lg0, 8);
        lg0 += __shfl_xor(lg0, 4);
        lg0 += __shfl_xor(lg0, 2);
        lg0 += __shfl_xor(lg0, 1);
        float e0 = exp2f(lg0);
        d += e0;
        a0 += e0 * x00;
        a1 += e0 * x01;
    }
    if (node < n) {
        float inv = 1.f / d;
        float2 o;
        o.x = a0 * inv + bias[2 * l + 0]; o.x = fmaxf(o.x, 0.f);
        o.y = a1 * inv + bias[2 * l + 1]; o.y = fmaxf(o.y, 0.f);
        *(float2*)(h1 + (size_t)node * D1 + 2 * l) = o;
    }
}

// ============ fused GATv2 aggregation + head, layer 2 ============
// 256 thr = 4 nodes (1 wave each); 4 comps/lane; head = 16 lanes.
__global__ __launch_bounds__(256) void k_agg2(
        const unsigned short* __restrict__ xl, const float* __restrict__ xr,
        const float* __restrict__ att, const float* __restrict__ b2,
        const float* __restrict__ W3, const float* __restrict__ b3,
        const int* __restrict__ rp, const int* __restrict__ deg,
        const int* __restrict__ eord, float* __restrict__ out, int n) {
    int t = threadIdx.x;
    int node = blockIdx.x * 4 + (t >> 6);
    int l = t & 63;
    int nd = (node < n) ? node : n - 1;
    float4 xrv = *(const float4*)(xr + (size_t)nd * D2 + 4 * l);
    float4 av  = *(const float4*)(att + 4 * l);
    av.x *= LOG2E; av.y *= LOG2E; av.z *= LOG2E; av.w *= LOG2E;
    int start = __builtin_amdgcn_readfirstlane(rp[nd]);
    int cnt   = (node < n) ? deg[nd] : 0;
    cnt = __builtin_amdgcn_readfirstlane(cnt);
    const uint2* xlp = (const uint2*)xl;   // row stride 64 uint2
    float d = 0.f, a0 = 0.f, a1 = 0.f, a2 = 0.f, a3 = 0.f;
    int cnt4 = cnt & ~3;
    uint2 r0, r1, r2, r3;
    if (cnt4 > 0) {
        int i0 = eord[start + 0], i1 = eord[start + 1];
        int i2 = eord[start + 2], i3 = eord[start + 3];
        r0 = xlp[(size_t)i0 * 64 + l]; r1 = xlp[(size_t)i1 * 64 + l];
        r2 = xlp[(size_t)i2 * 64 + l]; r3 = xlp[(size_t)i3 * 64 + l];
    }
    for (int j = 0; j < cnt4; j += 4) {
        uint2 p0 = r0, p1 = r1, p2 = r2, p3 = r3;
        int jn = j + 4;
        if (jn < cnt4) {
            int i0 = eord[start + jn + 0], i1 = eord[start + jn + 1];
            int i2 = eord[start + jn + 2], i3 = eord[start + jn + 3];
            r0 = xlp[(size_t)i0 * 64 + l]; r1 = xlp[(size_t)i1 * 64 + l];
            r2 = xlp[(size_t)i2 * 64 + l]; r3 = xlp[(size_t)i3 * 64 + l];
        }
        float x00 = bflo(p0.x), x01 = bfhi(p0.x), x02 = bflo(p0.y), x03 = bfhi(p0.y);
        float x10 = bflo(p1.x), x11 = bfhi(p1.x), x12 = bflo(p1.y), x13 = bfhi(p1.y);
        float x20 = bflo(p2.x), x21 = bfhi(p2.x), x22 = bflo(p2.y), x23 = bfhi(p2.y);
        float x30 = bflo(p3.x), x31 = bfhi(p3.x), x32 = bflo(p3.y), x33 = bfhi(p3.y);
        float v, lg0, lg1, lg2, lg3;
        v = x00 + xrv.x; v = fmaxf(v, SLOPE * v); lg0  = av.x * v;
        v = x01 + xrv.y; v = fmaxf(v, SLOPE * v); lg0 += av.y * v;
        v = x02 + xrv.z; v = fmaxf(v, SLOPE * v); lg0 += av.z * v;
        v = x03 + xrv.w; v = fmaxf(v, SLOPE * v); lg0 += av.w * v;
        v = x10 + xrv.x; v = fmaxf(v, SLOPE * v); lg1  = av.x * v;
        v = x11 + xrv.y; v = fmaxf(v, SLOPE * v); lg1 += av.y * v;
        v = x12 + xrv.z; v = fmaxf(v, SLOPE * v); lg1 += av.z * v;
        v = x13 + xrv.w; v = fmaxf(v, SLOPE * v); lg1 += av.w * v;
        v = x20 + xrv.x; v = fmaxf(v, SLOPE * v); lg2  = av.x * v;
        v = x21 + xrv.y; v = fmaxf(v, SLOPE * v); lg2 += av.y * v;
        v = x22 + xrv.z; v = fmaxf(v, SLOPE * v); lg2 += av.z * v;
        v = x23 + xrv.w; v = fmaxf(v, SLOPE * v); lg2 += av.w * v;
        v = x30 + xrv.x; v = fmaxf(v, SLOPE * v); lg3  = av.x * v;
        v = x31 + xrv.y; v = fmaxf(v, SLOPE * v); lg3 += av.y * v;
        v = x32 + xrv.z; v = fmaxf(v, SLOPE * v); lg3 += av.z * v;
        v = x33 + xrv.w; v = fmaxf(v, SLOPE * v); lg3 += av.w * v;
        lg0 += __shfl_xor(lg0, 8); lg1 += __shfl_xor(lg1, 8);
        lg2 += __shfl_xor(lg2, 8); lg3 += __shfl_xor(lg3, 8);
        lg0 += __shfl_xor(lg0, 4); lg1 += __shfl_xor(lg1, 4);
        lg2 += __shfl_xor(lg2, 4); lg3 += __shfl_xor(lg3, 4);
        lg0 += __shfl_xor(lg0, 2); lg1 += __shfl_xor(lg1, 2);
        lg2 += __shfl_xor(lg2, 2); lg3 += __shfl_xor(lg3, 2);
        lg0 += __shfl_xor(lg0, 1); lg1 += __shfl_xor(lg1, 1);
        lg2 += __shfl_xor(lg2, 1); lg3 += __shfl_xor(lg3, 1);
        float e0 = exp2f(lg0), e1 = exp2f(lg1);
        float e2 = exp2f(lg2), e3 = exp2f(lg3);
        d += (e0 + e1) + (e2 + e3);
        a0 += e0 * x00 + e1 * x10 + e2 * x20 + e3 * x30;
        a1 += e0 * x01 + e1 * x11 + e2 * x21 + e3 * x31;
        a2 += e0 * x02 + e1 * x12 + e2 * x22 + e3 * x32;
        a3 += e0 * x03 + e1 * x13 + e2 * x23 + e3 * x33;
    }
    for (int j = cnt4; j < cnt; ++j) {
        int s0 = eord[start + j];
        uint2 p0 = xlp[(size_t)s0 * 64 + l];
        float x00 = bflo(p0.x), x01 = bfhi(p0.x), x02 = bflo(p0.y), x03 = bfhi(p0.y);
        float v, lg0;
        v = x00 + xrv.x; v = fmaxf(v, SLOPE * v); lg0  = av.x * v;
        v = x01 + xrv.y; v = fmaxf(v, SLOPE * v); lg0 += av.y * v;
        v = x02 + xrv.z; v = fmaxf(v, SLOPE * v); lg0 += av.z * v;
        v = x03 + xrv.w; v = fmaxf(v, SLOPE * v); lg0 += av.w * v;
        lg0 += __shfl_xor(lg0, 8);
        lg0 += __shfl_xor(lg0, 4);
        lg0 += __shfl_xor(lg0, 2);
        lg0 += __shfl_xor(lg0, 1);
        float e0 = exp2f(lg0);
        d += e0;
        a0 += e0 * x00; a1 += e0 * x01; a2 += e0 * x02; a3 += e0 * x03;
    }
    // wave-local epilogue
    float inv = 1.f / d;
    float v0 = a0 * inv, v1 = a1 * inv, v2 = a2 * inv, v3 = a3 * inv;
    v0 += __shfl_xor(v0, 16); v1 += __shfl_xor(v1, 16);
    v2 += __shfl_xor(v2, 16); v3 += __shfl_xor(v3, 16);
    v0 += __shfl_xor(v0, 32); v1 += __shfl_xor(v1, 32);
    v2 += __shfl_xor(v2, 32); v3 += __shfl_xor(v3, 32);
    int c0 = 4 * (l & 15);
    v0 = fmaxf(0.25f * v0 + b2[c0 + 0], 0.f);
    v1 = fmaxf(0.25f * v1 + b2[c0 + 1], 0.f);
    v2 = fmaxf(0.25f * v2 + b2[c0 + 2], 0.f);
    v3 = fmaxf(0.25f * v3 + b2[c0 + 3], 0.f);
    float p0, p1, p2, p3, p4;
    {
        const float* w0 = W3 + (c0 + 0) * 5;
        const float* w1 = W3 + (c0 + 1) * 5;
        const float* w2 = W3 + (c0 + 2) * 5;
        const float* w3 = W3 + (c0 + 3) * 5;
        p0 = v0 * w0[0] + v1 * w1[0] + v2 * w2[0] + v3 * w3[0];
        p1 = v0 * w0[1] + v1 * w1[1] + v2 * w2[1] + v3 * w3[1];
        p2 = v0 * w0[2] + v1 * w1[2] + v2 * w2[2] + v3 * w3[2];
        p3 = v0 * w0[3] + v1 * w1[3] + v2 * w2[3] + v3 * w3[3];
        p4 = v0 * w0[4] + v1 * w1[4] + v2 * w2[4] + v3 * w3[4];
    }
#pragma unroll
    for (int off = 1; off < 16; off <<= 1) {
        p0 += __shfl_xor(p0, off); p1 += __shfl_xor(p1, off);
        p2 += __shfl_xor(p2, off); p3 += __shfl_xor(p3, off);
        p4 += __shfl_xor(p4, off);
    }
    if (l == 0 && node < n) {
        float* o = out + (size_t)node * 5;
        o[0] = 1.f / (1.f + __expf(-(p0 + b3[0])));
        o[1] = 1.f / (1.f + __expf(-(p1 + b3[1])));
        o[2] = 1.f / (1.f + __expf(-(p2 + b3[2])));
        o[3] = 1.f / (1.f + __expf(-(p3 + b3[3])));
        o[4] = 1.f / (1.f + __expf(-(p4 + b3[4])));
    }
}

extern "C" void kernel_launch(void* const* d_in, const int* in_sizes, int n_in,
                              void* d_out, int out_size, void* d_ws, size_t ws_size,
                              hipStream_t stream) {
    const float* x     = (const float*)d_in[0];
    const int*   ei    = (const int*)d_in[1];
    const float* lb    = (const float*)d_in[2];
    const float* ub    = (const float*)d_in[3];
    const float* W1l   = (const float*)d_in[4];
    const float* b1l   = (const float*)d_in[5];
    const float* W1r   = (const float*)d_in[6];
    const float* b1r   = (const float*)d_in[7];
    const float* att1  = (const float*)d_in[8];
    const float* bias1 = (const float*)d_in[9];
    const float* W2l   = (const float*)d_in[10];
    const float* b2l   = (const float*)d_in[11];
    const float* W2r   = (const float*)d_in[12];
    const float* b2r   = (const float*)d_in[13];
    const float* att2  = (const float*)d_in[14];
    const float* bias2 = (const float*)d_in[15];
    const float* W3    = (const float*)d_in[16];
    const float* b3    = (const float*)d_in[17];

    int n  = in_sizes[0] / CIN;
    int E  = in_sizes[1] / 2;
    int ET = E + n;

    char* ws = (char*)d_ws;
    size_t off = 0;
    auto alloc = [&](size_t nbytes) {
        void* p = ws + off;
        off += (nbytes + 255) & ~(size_t)255;
        return p;
    };
    unsigned short* xl1 = (unsigned short*)alloc((size_t)n * D1 * 2);
    float*          xr1 = (float*)alloc((size_t)n * D1 * 4);
    float*          h1  = (float*)alloc((size_t)n * D1 * 4);
    unsigned short* xl2 = (unsigned short*)alloc((size_t)n * D2 * 2);
    float*          xr2 = (float*)alloc((size_t)n * D2 * 4);
    int* deg  = (int*)alloc((size_t)n * 4);
    int* cur  = (int*)alloc((size_t)n * 4);
    int* rp   = (int*)alloc((size_t)n * 4);
    int* eord = (int*)alloc((size_t)ET * 4);

    // ---- CSR build ----
    hipMemsetAsync(deg, 0, (size_t)n * 4, stream);
    k_hist<<<(ET + 255) / 256, 256, 0, stream>>>(ei, E, ET, deg);
    k_scan_one<<<1, 1024, 0, stream>>>(deg, rp, cur, n);
    k_fill<<<(ET + 255) / 256, 256, 0, stream>>>(ei, E, ET, rp, cur, eord);

    // ---- layer 1 ----
    k_lin1<<<(n + 15) / 16, 256, 0, stream>>>(x, lb, ub, W1l, b1l, W1r, b1r,
                                              xl1, xr1, n);
    k_agg1<<<(n + 3) / 4, 256, 0, stream>>>(xl1, xr1, att1, bias1, rp, deg,
                                            eord, h1, n);

    // ---- layer 2 ----
    dim3 g2((n + 127) / 128, 4);
    k_lin2<<<g2, 256, 0, stream>>>(h1, W2l, b2l, W2r, b2r, xl2, xr2, n);
    k_agg2<<<(n + 3) / 4, 256, 0, stream>>>(xl2, xr2, att2, bias2, W3, b3,
                                            rp, deg, eord, (float*)d_out, n);
}

// Round 6
// 221.927 us; speedup vs baseline: 1.0620x; 1.0620x over previous
//
#include <hip/hip_runtime.h>

#define H 4
#define D1 128
#define D2 256
#define CIN 16
#define SLOPE 0.2f
#define LOG2E 1.4426950408889634f

typedef short short8v __attribute__((ext_vector_type(8)));
typedef float float4v __attribute__((ext_vector_type(4)));

__device__ __forceinline__ float bflo(unsigned u) { return __uint_as_float(u << 16); }
__device__ __forceinline__ float bfhi(unsigned u) { return __uint_as_float(u & 0xFFFF0000u); }
__device__ __forceinline__ unsigned short f2bf(float f) {
    unsigned int u = __float_as_uint(f);
    u += 0x7FFFu + ((u >> 16) & 1u);
    return (unsigned short)(u >> 16);
}

// ============ CSR build ============
__global__ void k_hist(const int* __restrict__ ei, int E, int ET,
                       int* __restrict__ deg) {
    int idx = blockIdx.x * blockDim.x + threadIdx.x;
    if (idx >= ET) return;
    int dst = (idx < E) ? ei[E + idx] : idx - E;
    atomicAdd(&deg[dst], 1);
}

__global__ __launch_bounds__(1024) void k_scan_one(
        const int* __restrict__ deg, int* __restrict__ rp,
        int* __restrict__ cur, int n) {
    __shared__ int wsum[16];
    int t = threadIdx.x;
    int lane = t & 63, w = t >> 6;
    int base = t * 32;
    int loc[32];
    int s = 0;
#pragma unroll
    for (int k = 0; k < 32; ++k) {
        int idx = base + k;
        int v = (idx < n) ? deg[idx] : 0;
        loc[k] = s;
        s += v;
    }
    int inc = s;
#pragma unroll
    for (int off = 1; off < 64; off <<= 1) {
        int u = __shfl_up(inc, off, 64);
        if (lane >= off) inc += u;
    }
    int excl = inc - s;
    if (lane == 63) wsum[w] = inc;
    __syncthreads();
    if (w == 0) {
        int v = (lane < 16) ? wsum[lane] : 0;
        int winc = v;
#pragma unroll
        for (int off = 1; off < 16; off <<= 1) {
            int u = __shfl_up(winc, off, 64);
            if (lane >= off) winc += u;
        }
        if (lane < 16) wsum[lane] = winc - v;
    }
    __syncthreads();
    int offw = wsum[w] + excl;
#pragma unroll
    for (int k = 0; k < 32; ++k) {
        int idx = base + k;
        if (idx < n) { rp[idx] = offw + loc[k]; cur[idx] = 0; }
    }
}

__global__ void k_fill(const int* __restrict__ ei, int E, int ET,
                       const int* __restrict__ rp, int* __restrict__ cur,
                       int* __restrict__ eord) {
    int idx = blockIdx.x * blockDim.x + threadIdx.x;
    if (idx >= ET) return;
    int src, dst;
    if (idx < E) { src = ei[idx]; dst = ei[E + idx]; }
    else         { src = dst = idx - E; }
    int pos = atomicAdd(&cur[dst], 1);
    eord[rp[dst] + pos] = src;
}

// ============ W2 convert+transpose: [128][256]x2 fp32 -> [512][128] bf16 ===
__global__ __launch_bounds__(256) void k_cvtW2(
        const float* __restrict__ Wl, const float* __restrict__ Wr,
        unsigned short* __restrict__ W2t) {
    int idx = blockIdx.x * 256 + threadIdx.x;   // 0..65535
    int k = idx >> 9, c = idx & 511;
    float v = (c < 256) ? Wl[k * 256 + c] : Wr[k * 256 + (c - 256)];
    W2t[(size_t)c * 128 + k] = f2bf(v);
}

// ============ layer-1 linear ============
__global__ __launch_bounds__(256) void k_lin1(
        const float* __restrict__ x, const float* __restrict__ lb,
        const float* __restrict__ ub,
        const float* __restrict__ Wl, const float* __restrict__ bl,
        const float* __restrict__ Wr, const float* __restrict__ br,
        unsigned short* __restrict__ xl, float* __restrict__ xr, int n) {
    __shared__ float Wls[CIN][D1];
    __shared__ float Wrs[CIN][D1];
    __shared__ float ys[16][CIN];
    int t = threadIdx.x;
    int i0 = blockIdx.x * 16;
#pragma unroll
    for (int i = 0; i < 8; ++i) {
        int flat = t + 256 * i;
        int k = flat >> 7, c = flat & 127;
        Wls[k][c] = Wl[k * D1 + c];
        Wrs[k][c] = Wr[k * D1 + c];
    }
    {
        int node = t >> 4, k = t & 15;
        int gi = i0 + node;
        float xv = (gi < n) ? x[(size_t)gi * CIN + k] : 0.f;
        ys[node][k] = (xv - lb[k]) / (ub[k] - lb[k]);
    }
    __syncthreads();
    int c = t & 127;
    bool left = t < 128;
    const float (*Ws)[D1] = left ? Wls : Wrs;
    float bias = left ? bl[c] : br[c];
    for (int j = 0; j < 16; ++j) {
        float acc = bias;
#pragma unroll
        for (int k = 0; k < CIN; ++k) acc += ys[j][k] * Ws[k][c];
        int gi = i0 + j;
        if (gi < n) {
            if (left) xl[(size_t)gi * D1 + c] = f2bf(acc);
            else      xr[(size_t)gi * D1 + c] = acc;
        }
    }
}

// ============ layer-2 linear: bf16 MFMA GEMM ============
// M=n, K=128, N=512. BM=128, BN=128 (grid.y: col0 = y*128; y<2 -> xl2, else xr2)
// 4 waves in 2x2; wave = 64x64 out = 4x4 frags of 16x16; mfma_f32_16x16x32_bf16.
// LDS swizzle: ushort idx ^= (row&15)<<3  (16B-slot XOR, bijective per row).
__global__ __launch_bounds__(256) void k_lin2_mfma(
        const unsigned short* __restrict__ h1b,   // [n][128] bf16
        const unsigned short* __restrict__ W2t,   // [512][128] bf16
        const float* __restrict__ b2l, const float* __restrict__ b2r,
        unsigned short* __restrict__ xl2,         // [n][256] bf16
        unsigned short* __restrict__ xr2,         // [n][256] bf16
        int n) {
    __shared__ unsigned short At[128 * 128];
    __shared__ unsigned short Bt[128 * 128];
    int t = threadIdx.x;
    int row0 = blockIdx.x * 128;
    int col0 = blockIdx.y * 128;

    // stage A (h1b rows, zero-padded) and B (W2t rows = output cols)
    {
        int r = t >> 1, hh = (t & 1) * 64;
        bool ok = (row0 + r) < n;
        const unsigned short* gA = h1b + (size_t)(row0 + r) * 128 + hh;
        const unsigned short* gB = W2t + (size_t)(col0 + r) * 128 + hh;
#pragma unroll
        for (int i = 0; i < 8; ++i) {
            uint4 vA = ok ? *(const uint4*)(gA + i * 8) : make_uint4(0, 0, 0, 0);
            uint4 vB = *(const uint4*)(gB + i * 8);
            int col = hh + i * 8;
            int idx = (r * 128 + col) ^ ((r & 15) << 3);
            *(uint4*)&At[idx] = vA;
            *(uint4*)&Bt[idx] = vB;
        }
    }
    __syncthreads();

    int w = t >> 6, l = t & 63;
    int wr = w >> 1, wc = w & 1;
    float4v acc[4][4];
#pragma unroll
    for (int m = 0; m < 4; ++m)
#pragma unroll
        for (int nn = 0; nn < 4; ++nn) acc[m][nn] = (float4v)0.f;

#pragma unroll
    for (int ks = 0; ks < 4; ++ks) {
        int kb = ks * 32 + ((l >> 4) << 3);
        short8v a[4], b[4];
#pragma unroll
        for (int m = 0; m < 4; ++m) {
            int r = wr * 64 + m * 16 + (l & 15);
            a[m] = *(const short8v*)&At[(r * 128 + kb) ^ ((r & 15) << 3)];
        }
#pragma unroll
        for (int nn = 0; nn < 4; ++nn) {
            int c = wc * 64 + nn * 16 + (l & 15);
            b[nn] = *(const short8v*)&Bt[(c * 128 + kb) ^ ((c & 15) << 3)];
        }
#pragma unroll
        for (int m = 0; m < 4; ++m)
#pragma unroll
            for (int nn = 0; nn < 4; ++nn)
                acc[m][nn] = __builtin_amdgcn_mfma_f32_16x16x32_bf16(
                    a[m], b[nn], acc[m][nn], 0, 0, 0);
    }

    // epilogue: +bias, store bf16.  C frag: col=l&15, row=(l>>4)*4+r
    unsigned short* outbuf = (col0 < 256) ? xl2 : xr2;
    const float* bp = (col0 < 256) ? b2l : b2r;
    int cb = (col0 < 256) ? col0 : col0 - 256;
#pragma unroll
    for (int nn = 0; nn < 4; ++nn) {
        int colc = cb + wc * 64 + nn * 16 + (l & 15);
        float bv = bp[colc];
#pragma unroll
        for (int m = 0; m < 4; ++m) {
            int rbase = row0 + wr * 64 + m * 16 + ((l >> 4) << 2);
#pragma unroll
            for (int r = 0; r < 4; ++r) {
                int row = rbase + r;
                if (row < n)
                    outbuf[(size_t)row * 256 + colc] = f2bf(acc[m][nn][r] + bv);
            }
        }
    }
}

// ============ fused GATv2 aggregation, layer 1 ============
__global__ __launch_bounds__(256) void k_agg1(
        const unsigned short* __restrict__ xl, const float* __restrict__ xr,
        const float* __restrict__ att, const float* __restrict__ bias,
        const int* __restrict__ rp, const int* __restrict__ deg,
        const int* __restrict__ eord, unsigned short* __restrict__ h1b, int n) {
    int t = threadIdx.x;
    int node = blockIdx.x * 4 + (t >> 6);
    int l = t & 63;
    int nd = (node < n) ? node : n - 1;
    float2 xrv = *(const float2*)(xr + (size_t)nd * D1 + 2 * l);
    float2 av  = *(const float2*)(att + 2 * l);
    av.x *= LOG2E; av.y *= LOG2E;
    int start = __builtin_amdgcn_readfirstlane(rp[nd]);
    int cnt   = (node < n) ? deg[nd] : 0;
    cnt = __builtin_amdgcn_readfirstlane(cnt);
    const unsigned* xlp = (const unsigned*)xl;
    float d = 0.f, a0 = 0.f, a1 = 0.f;
    int cnt4 = cnt & ~3;
    unsigned r0, r1, r2, r3;
    if (cnt4 > 0) {
        int i0 = eord[start + 0], i1 = eord[start + 1];
        int i2 = eord[start + 2], i3 = eord[start + 3];
        r0 = xlp[(size_t)i0 * 64 + l]; r1 = xlp[(size_t)i1 * 64 + l];
        r2 = xlp[(size_t)i2 * 64 + l]; r3 = xlp[(size_t)i3 * 64 + l];
    }
    for (int j = 0; j < cnt4; j += 4) {
        unsigned p0 = r0, p1 = r1, p2 = r2, p3 = r3;
        int jn = j + 4;
        if (jn < cnt4) {
            int i0 = eord[start + jn + 0], i1 = eord[start + jn + 1];
            int i2 = eord[start + jn + 2], i3 = eord[start + jn + 3];
            r0 = xlp[(size_t)i0 * 64 + l]; r1 = xlp[(size_t)i1 * 64 + l];
            r2 = xlp[(size_t)i2 * 64 + l]; r3 = xlp[(size_t)i3 * 64 + l];
        }
        float x00 = bflo(p0), x01 = bfhi(p0);
        float x10 = bflo(p1), x11 = bfhi(p1);
        float x20 = bflo(p2), x21 = bfhi(p2);
        float x30 = bflo(p3), x31 = bfhi(p3);
        float v, lg0, lg1, lg2, lg3;
        v = x00 + xrv.x; v = fmaxf(v, SLOPE * v); lg0  = av.x * v;
        v = x01 + xrv.y; v = fmaxf(v, SLOPE * v); lg0 += av.y * v;
        v = x10 + xrv.x; v = fmaxf(v, SLOPE * v); lg1  = av.x * v;
        v = x11 + xrv.y; v = fmaxf(v, SLOPE * v); lg1 += av.y * v;
        v = x20 + xrv.x; v = fmaxf(v, SLOPE * v); lg2  = av.x * v;
        v = x21 + xrv.y; v = fmaxf(v, SLOPE * v); lg2 += av.y * v;
        v = x30 + xrv.x; v = fmaxf(v, SLOPE * v); lg3  = av.x * v;
        v = x31 + xrv.y; v = fmaxf(v, SLOPE * v); lg3 += av.y * v;
        lg0 += __shfl_xor(lg0, 8); lg1 += __shfl_xor(lg1, 8);
        lg2 += __shfl_xor(lg2, 8); lg3 += __shfl_xor(lg3, 8);
        lg0 += __shfl_xor(lg0, 4); lg1 += __shfl_xor(lg1, 4);
        lg2 += __shfl_xor(lg2, 4); lg3 += __shfl_xor(lg3, 4);
        lg0 += __shfl_xor(lg0, 2); lg1 += __shfl_xor(lg1, 2);
        lg2 += __shfl_xor(lg2, 2); lg3 += __shfl_xor(lg3, 2);
        lg0 += __shfl_xor(lg0, 1); lg1 += __shfl_xor(lg1, 1);
        lg2 += __shfl_xor(lg2, 1); lg3 += __shfl_xor(lg3, 1);
        float e0 = exp2f(lg0), e1 = exp2f(lg1);
        float e2 = exp2f(lg2), e3 = exp2f(lg3);
        d += (e0 + e1) + (e2 + e3);
        a0 += e0 * x00 + e1 * x10 + e2 * x20 + e3 * x30;
        a1 += e0 * x01 + e1 * x11 + e2 * x21 + e3 * x31;
    }
    for (int j = cnt4; j < cnt; ++j) {
        int s0 = eord[start + j];
        unsigned p0 = xlp[(size_t)s0 * 64 + l];
        float x00 = bflo(p0), x01 = bfhi(p0);
        float v, lg0;
        v = x00 + xrv.x; v = fmaxf(v, SLOPE * v); lg0  = av.x * v;
        v = x01 + xrv.y; v = fmaxf(v, SLOPE * v); lg0 += av.y * v;
        lg0 += __shfl_xor(lg0, 8);
        lg0 += __shfl_xor(lg0, 4);
        lg0 += __shfl_xor(lg0, 2);
        lg0 += __shfl_xor(lg0, 1);
        float e0 = exp2f(lg0);
        d += e0;
        a0 += e0 * x00;
        a1 += e0 * x01;
    }
    if (node < n) {
        float inv = 1.f / d;
        float o0 = fmaxf(a0 * inv + bias[2 * l + 0], 0.f);
        float o1 = fmaxf(a1 * inv + bias[2 * l + 1], 0.f);
        ((unsigned*)h1b)[(size_t)node * 64 + l] =
            ((unsigned)f2bf(o1) << 16) | f2bf(o0);
    }
}

// ============ fused GATv2 aggregation + head, layer 2 ============
__global__ __launch_bounds__(256) void k_agg2(
        const unsigned short* __restrict__ xl, const unsigned short* __restrict__ xr,
        const float* __restrict__ att, const float* __restrict__ b2,
        const float* __restrict__ W3, const float* __restrict__ b3,
        const int* __restrict__ rp, const int* __restrict__ deg,
        const int* __restrict__ eord, float* __restrict__ out, int n) {
    int t = threadIdx.x;
    int node = blockIdx.x * 4 + (t >> 6);
    int l = t & 63;
    int nd = (node < n) ? node : n - 1;
    const uint2* xrp = (const uint2*)xr;
    uint2 xru = xrp[(size_t)nd * 64 + l];
    float4 xrv = make_float4(bflo(xru.x), bfhi(xru.x), bflo(xru.y), bfhi(xru.y));
    float4 av  = *(const float4*)(att + 4 * l);
    av.x *= LOG2E; av.y *= LOG2E; av.z *= LOG2E; av.w *= LOG2E;
    int start = __builtin_amdgcn_readfirstlane(rp[nd]);
    int cnt   = (node < n) ? deg[nd] : 0;
    cnt = __builtin_amdgcn_readfirstlane(cnt);
    const uint2* xlp = (const uint2*)xl;
    float d = 0.f, a0 = 0.f, a1 = 0.f, a2 = 0.f, a3 = 0.f;
    int cnt4 = cnt & ~3;
    uint2 r0, r1, r2, r3;
    if (cnt4 > 0) {
        int i0 = eord[start + 0], i1 = eord[start + 1];
        int i2 = eord[start + 2], i3 = eord[start + 3];
        r0 = xlp[(size_t)i0 * 64 + l]; r1 = xlp[(size_t)i1 * 64 + l];
        r2 = xlp[(size_t)i2 * 64 + l]; r3 = xlp[(size_t)i3 * 64 + l];
    }
    for (int j = 0; j < cnt4; j += 4) {
        uint2 p0 = r0, p1 = r1, p2 = r2, p3 = r3;
        int jn = j + 4;
        if (jn < cnt4) {
            int i0 = eord[start + jn + 0], i1 = eord[start + jn + 1];
            int i2 = eord[start + jn + 2], i3 = eord[start + jn + 3];
            r0 = xlp[(size_t)i0 * 64 + l]; r1 = xlp[(size_t)i1 * 64 + l];
            r2 = xlp[(size_t)i2 * 64 + l]; r3 = xlp[(size_t)i3 * 64 + l];
        }
        float x00 = bflo(p0.x), x01 = bfhi(p0.x), x02 = bflo(p0.y), x03 = bfhi(p0.y);
        float x10 = bflo(p1.x), x11 = bfhi(p1.x), x12 = bflo(p1.y), x13 = bfhi(p1.y);
        float x20 = bflo(p2.x), x21 = bfhi(p2.x), x22 = bflo(p2.y), x23 = bfhi(p2.y);
        float x30 = bflo(p3.x), x31 = bfhi(p3.x), x32 = bflo(p3.y), x33 = bfhi(p3.y);
        float v, lg0, lg1, lg2, lg3;
        v = x00 + xrv.x; v = fmaxf(v, SLOPE * v); lg0  = av.x * v;
        v = x01 + xrv.y; v = fmaxf(v, SLOPE * v); lg0 += av.y * v;
        v = x02 + xrv.z; v = fmaxf(v, SLOPE * v); lg0 += av.z * v;
        v = x03 + xrv.w; v = fmaxf(v, SLOPE * v); lg0 += av.w * v;
        v = x10 + xrv.x; v = fmaxf(v, SLOPE * v); lg1  = av.x * v;
        v = x11 + xrv.y; v = fmaxf(v, SLOPE * v); lg1 += av.y * v;
        v = x12 + xrv.z; v = fmaxf(v, SLOPE * v); lg1 += av.z * v;
        v = x13 + xrv.w; v = fmaxf(v, SLOPE * v); lg1 += av.w * v;
        v = x20 + xrv.x; v = fmaxf(v, SLOPE * v); lg2  = av.x * v;
        v = x21 + xrv.y; v = fmaxf(v, SLOPE * v); lg2 += av.y * v;
        v = x22 + xrv.z; v = fmaxf(v, SLOPE * v); lg2 += av.z * v;
        v = x23 + xrv.w; v = fmaxf(v, SLOPE * v); lg2 += av.w * v;
        v = x30 + xrv.x; v = fmaxf(v, SLOPE * v); lg3  = av.x * v;
        v = x31 + xrv.y; v = fmaxf(v, SLOPE * v); lg3 += av.y * v;
        v = x32 + xrv.z; v = fmaxf(v, SLOPE * v); lg3 += av.z * v;
        v = x33 + xrv.w; v = fmaxf(v, SLOPE * v); lg3 += av.w * v;
        lg0 += __shfl_xor(lg0, 8); lg1 += __shfl_xor(lg1, 8);
        lg2 += __shfl_xor(lg2, 8); lg3 += __shfl_xor(lg3, 8);
        lg0 += __shfl_xor(lg0, 4); lg1 += __shfl_xor(lg1, 4);
        lg2 += __shfl_xor(lg2, 4); lg3 += __shfl_xor(lg3, 4);
        lg0 += __shfl_xor(lg0, 2); lg1 += __shfl_xor(lg1, 2);
        lg2 += __shfl_xor(lg2, 2); lg3 += __shfl_xor(lg3, 2);
        lg0 += __shfl_xor(lg0, 1); lg1 += __shfl_xor(lg1, 1);
        lg2 += __shfl_xor(lg2, 1); lg3 += __shfl_xor(lg3, 1);
        float e0 = exp2f(lg0), e1 = exp2f(lg1);
        float e2 = exp2f(lg2), e3 = exp2f(lg3);
        d += (e0 + e1) + (e2 + e3);
        a0 += e0 * x00 + e1 * x10 + e2 * x20 + e3 * x30;
        a1 += e0 * x01 + e1 * x11 + e2 * x21 + e3 * x31;
        a2 += e0 * x02 + e1 * x12 + e2 * x22 + e3 * x32;
        a3 += e0 * x03 + e1 * x13 + e2 * x23 + e3 * x33;
    }
    for (int j = cnt4; j < cnt; ++j) {
        int s0 = eord[start + j];
        uint2 p0 = xlp[(size_t)s0 * 64 + l];
        float x00 = bflo(p0.x), x01 = bfhi(p0.x), x02 = bflo(p0.y), x03 = bfhi(p0.y);
        float v, lg0;
        v = x00 + xrv.x; v = fmaxf(v, SLOPE * v); lg0  = av.x * v;
        v = x01 + xrv.y; v = fmaxf(v, SLOPE * v); lg0 += av.y * v;
        v = x02 + xrv.z; v = fmaxf(v, SLOPE * v); lg0 += av.z * v;
        v = x03 + xrv.w; v = fmaxf(v, SLOPE * v); lg0 += av.w * v;
        lg0 += __shfl_xor(lg0, 8);
        lg0 += __shfl_xor(lg0, 4);
        lg0 += __shfl_xor(lg0, 2);
        lg0 += __shfl_xor(lg0, 1);
        float e0 = exp2f(lg0);
        d += e0;
        a0 += e0 * x00; a1 += e0 * x01; a2 += e0 * x02; a3 += e0 * x03;
    }
    float inv = 1.f / d;
    float v0 = a0 * inv, v1 = a1 * inv, v2 = a2 * inv, v3 = a3 * inv;
    v0 += __shfl_xor(v0, 16); v1 += __shfl_xor(v1, 16);
    v2 += __shfl_xor(v2, 16); v3 += __shfl_xor(v3, 16);
    v0 += __shfl_xor(v0, 32); v1 += __shfl_xor(v1, 32);
    v2 += __shfl_xor(v2, 32); v3 += __shfl_xor(v3, 32);
    int c0 = 4 * (l & 15);
    v0 = fmaxf(0.25f * v0 + b2[c0 + 0], 0.f);
    v1 = fmaxf(0.25f * v1 + b2[c0 + 1], 0.f);
    v2 = fmaxf(0.25f * v2 + b2[c0 + 2], 0.f);
    v3 = fmaxf(0.25f * v3 + b2[c0 + 3], 0.f);
    float p0, p1, p2, p3, p4;
    {
        const float* w0 = W3 + (c0 + 0) * 5;
        const float* w1 = W3 + (c0 + 1) * 5;
        const float* w2 = W3 + (c0 + 2) * 5;
        const float* w3 = W3 + (c0 + 3) * 5;
        p0 = v0 * w0[0] + v1 * w1[0] + v2 * w2[0] + v3 * w3[0];
        p1 = v0 * w0[1] + v1 * w1[1] + v2 * w2[1] + v3 * w3[1];
        p2 = v0 * w0[2] + v1 * w1[2] + v2 * w2[2] + v3 * w3[2];
        p3 = v0 * w0[3] + v1 * w1[3] + v2 * w2[3] + v3 * w3[3];
        p4 = v0 * w0[4] + v1 * w1[4] + v2 * w2[4] + v3 * w3[4];
    }
#pragma unroll
    for (int off = 1; off < 16; off <<= 1) {
        p0 += __shfl_xor(p0, off); p1 += __shfl_xor(p1, off);
        p2 += __shfl_xor(p2, off); p3 += __shfl_xor(p3, off);
        p4 += __shfl_xor(p4, off);
    }
    if (l == 0 && node < n) {
        float* o = out + (size_t)node * 5;
        o[0] = 1.f / (1.f + __expf(-(p0 + b3[0])));
        o[1] = 1.f / (1.f + __expf(-(p1 + b3[1])));
        o[2] = 1.f / (1.f + __expf(-(p2 + b3[2])));
        o[3] = 1.f / (1.f + __expf(-(p3 + b3[3])));
        o[4] = 1.f / (1.f + __expf(-(p4 + b3[4])));
    }
}

extern "C" void kernel_launch(void* const* d_in, const int* in_sizes, int n_in,
                              void* d_out, int out_size, void* d_ws, size_t ws_size,
                              hipStream_t stream) {
    const float* x     = (const float*)d_in[0];
    const int*   ei    = (const int*)d_in[1];
    const float* lb    = (const float*)d_in[2];
    const float* ub    = (const float*)d_in[3];
    const float* W1l   = (const float*)d_in[4];
    const float* b1l   = (const float*)d_in[5];
    const float* W1r   = (const float*)d_in[6];
    const float* b1r   = (const float*)d_in[7];
    const float* att1  = (const float*)d_in[8];
    const float* bias1 = (const float*)d_in[9];
    const float* W2l   = (const float*)d_in[10];
    const float* b2l   = (const float*)d_in[11];
    const float* W2r   = (const float*)d_in[12];
    const float* b2r   = (const float*)d_in[13];
    const float* att2  = (const float*)d_in[14];
    const float* bias2 = (const float*)d_in[15];
    const float* W3    = (const float*)d_in[16];
    const float* b3    = (const float*)d_in[17];

    int n  = in_sizes[0] / CIN;
    int E  = in_sizes[1] / 2;
    int ET = E + n;

    char* ws = (char*)d_ws;
    size_t off = 0;
    auto alloc = [&](size_t nbytes) {
        void* p = ws + off;
        off += (nbytes + 255) & ~(size_t)255;
        return p;
    };
    unsigned short* xl1 = (unsigned short*)alloc((size_t)n * D1 * 2);
    float*          xr1 = (float*)alloc((size_t)n * D1 * 4);
    unsigned short* h1b = (unsigned short*)alloc((size_t)n * D1 * 2);
    unsigned short* xl2 = (unsigned short*)alloc((size_t)n * D2 * 2);
    unsigned short* xr2 = (unsigned short*)alloc((size_t)n * D2 * 2);
    unsigned short* W2t = (unsigned short*)alloc((size_t)512 * 128 * 2);
    int* deg  = (int*)alloc((size_t)n * 4);
    int* cur  = (int*)alloc((size_t)n * 4);
    int* rp   = (int*)alloc((size_t)n * 4);
    int* eord = (int*)alloc((size_t)ET * 4);

    // ---- W2 convert + CSR build ----
    k_cvtW2<<<256, 256, 0, stream>>>(W2l, W2r, W2t);
    hipMemsetAsync(deg, 0, (size_t)n * 4, stream);
    k_hist<<<(ET + 255) / 256, 256, 0, stream>>>(ei, E, ET, deg);
    k_scan_one<<<1, 1024, 0, stream>>>(deg, rp, cur, n);
    k_fill<<<(ET + 255) / 256, 256, 0, stream>>>(ei, E, ET, rp, cur, eord);

    // ---- layer 1 ----
    k_lin1<<<(n + 15) / 16, 256, 0, stream>>>(x, lb, ub, W1l, b1l, W1r, b1r,
                                              xl1, xr1, n);
    k_agg1<<<(n + 3) / 4, 256, 0, stream>>>(xl1, xr1, att1, bias1, rp, deg,
                                            eord, h1b, n);

    // ---- layer 2 ----
    dim3 g2((n + 127) / 128, 4);
    k_lin2_mfma<<<g2, 256, 0, stream>>>(h1b, W2t, b2l, b2r, xl2, xr2, n);
    k_agg2<<<(n + 3) / 4, 256, 0, stream>>>(xl2, xr2, att2, bias2, W3, b3,
                                            rp, deg, eord, (float*)d_out, n);
}